// Round 1
// baseline (156.521 us; speedup 1.0000x reference)
//
#include <hip/hip_runtime.h>

#define SORT_N 4096  // next-pow2 >= D; here D == 4096

// ---------------------------------------------------------------------------
// Kernel A: exact k-th-largest threshold via in-LDS bitonic sort, then emit
// the selected kernel vector sel[d] = (kernel[d] < thr) ? 0 : kernel[d].
// Single block, 1024 threads. D=4096 floats = 16 KiB LDS.
// ---------------------------------------------------------------------------
__global__ void __launch_bounds__(1024)
select_threshold_kernel(const float* __restrict__ kern,
                        const int* __restrict__ kptr,
                        float* __restrict__ sel,
                        int D) {
    __shared__ float s[SORT_N];
    const int tid = threadIdx.x;
    const int nthr = blockDim.x;

    // load (pad with -inf so pads sink to the bottom of the ascending sort)
    for (int i = tid; i < SORT_N; i += nthr)
        s[i] = (i < D) ? kern[i] : -__builtin_inff();
    __syncthreads();

    // bitonic sort, ascending
    for (int k = 2; k <= SORT_N; k <<= 1) {
        for (int j = k >> 1; j > 0; j >>= 1) {
            for (int i = tid; i < SORT_N; i += nthr) {
                int ixj = i ^ j;
                if (ixj > i) {
                    float a = s[i];
                    float b = s[ixj];
                    bool asc = ((i & k) == 0);
                    if ((a > b) == asc) { s[i] = b; s[ixj] = a; }
                }
            }
            __syncthreads();
        }
    }

    // k-th largest = ascending-sorted[SORT_N - k] (pads are below all reals)
    const int kk = *kptr;
    const float thr = s[SORT_N - kk];

    for (int i = tid; i < D; i += nthr) {
        float v = kern[i];
        sel[i] = (v < thr) ? 0.0f : v;
    }
}

// ---------------------------------------------------------------------------
// Kernel B: out[b,d] = x[b,d] * sel[d], float4-vectorized grid-stride.
// sel is 16 KiB -> L1/L2 resident; pure HBM-streaming roofline.
// d4mask = D/4 - 1 (D is a power of two).
// ---------------------------------------------------------------------------
__global__ void __launch_bounds__(256)
bcast_mul_kernel(const float4* __restrict__ x,
                 const float4* __restrict__ sel,
                 float4* __restrict__ out,
                 int n4, int d4mask) {
    int idx = blockIdx.x * blockDim.x + threadIdx.x;
    int stride = gridDim.x * blockDim.x;
    for (int i = idx; i < n4; i += stride) {
        float4 xv = x[i];
        float4 sv = sel[i & d4mask];
        float4 o;
        o.x = xv.x * sv.x;
        o.y = xv.y * sv.y;
        o.z = xv.z * sv.z;
        o.w = xv.w * sv.w;
        out[i] = o;
    }
}

extern "C" void kernel_launch(void* const* d_in, const int* in_sizes, int n_in,
                              void* d_out, int out_size, void* d_ws, size_t ws_size,
                              hipStream_t stream) {
    const float* x    = (const float*)d_in[0];
    const float* kern = (const float*)d_in[1];
    const int*   kptr = (const int*)d_in[2];
    float* out = (float*)d_out;
    float* sel = (float*)d_ws;  // D floats = 16 KiB of scratch

    const int D = in_sizes[1];

    // Phase 1: exact threshold + selected kernel vector (single block)
    select_threshold_kernel<<<1, 1024, 0, stream>>>(kern, kptr, sel, D);

    // Phase 2: streaming broadcast multiply
    const int n4 = out_size / 4;          // out_size = B*D, divisible by 4
    const int d4mask = (D / 4) - 1;       // D is a power of two (4096)
    const int blocks = 2048;              // grid-stride; ~8 blocks/CU
    bcast_mul_kernel<<<blocks, 256, 0, stream>>>(
        (const float4*)x, (const float4*)sel, (float4*)out, n4, d4mask);
}

// Round 2
// 104.991 us; speedup vs baseline: 1.4908x; 1.4908x over previous
//
#include <hip/hip_runtime.h>

typedef float f32x4 __attribute__((ext_vector_type(4)));

// ---------------------------------------------------------------------------
// Kernel A: exact k-th-largest threshold via bitwise binary search on
// order-preserving uint transforms, then emit sel[d] = (kern[d]<thr)?0:kern[d].
// Single block, 256 threads, values held in registers (16/thread for D=4096).
// The kernel values span only ~16 ULPs, so after the min/max reduce the
// binary search runs ~4-5 iterations, each a cheap count+block-reduce.
// ---------------------------------------------------------------------------
__global__ void __launch_bounds__(256)
select_threshold_kernel(const float* __restrict__ kern,
                        const int* __restrict__ kptr,
                        float* __restrict__ sel,
                        int D) {
    const int tid  = threadIdx.x;
    const int lane = tid & 63;
    const int wid  = tid >> 6;

    __shared__ unsigned int s_umin[4], s_umax[4];
    __shared__ int s_cnt[4];

    // Load up to 16 values/thread into registers, as order-preserving uints:
    // for float f with bits b: u = b ^ ((int(b)>>31) | 0x80000000)
    // preserves total order (pos floats map above neg; uint compare == float compare).
    unsigned int u[16];
    #pragma unroll
    for (int j = 0; j < 16; ++j) {
        int i = tid + j * 256;
        if (i < D) {
            unsigned int b = __float_as_uint(kern[i]);
            u[j] = b ^ (unsigned int)(((int)b >> 31) | (int)0x80000000);
        } else {
            u[j] = 0u;  // pads sort below all real values
        }
    }

    // Block min/max reduce to find the common prefix (shrinks search to ~5 bits)
    unsigned int umin = 0xFFFFFFFFu, umax = 0u;
    #pragma unroll
    for (int j = 0; j < 16; ++j) {
        int i = tid + j * 256;
        if (i < D) { umin = min(umin, u[j]); umax = max(umax, u[j]); }
    }
    #pragma unroll
    for (int off = 32; off; off >>= 1) {
        umin = min(umin, (unsigned int)__shfl_down((int)umin, off, 64));
        umax = max(umax, (unsigned int)__shfl_down((int)umax, off, 64));
    }
    if (lane == 0) { s_umin[wid] = umin; s_umax[wid] = umax; }
    __syncthreads();
    umin = min(min(s_umin[0], s_umin[1]), min(s_umin[2], s_umin[3]));
    umax = max(max(s_umax[0], s_umax[1]), max(s_umax[2], s_umax[3]));

    // Bitwise binary search for t = ordered-uint of the k-th largest:
    // t = max value such that count(u >= t) >= k.
    const int kk = *kptr;
    unsigned int t;
    unsigned int xorv = umin ^ umax;
    if (xorv == 0u) {
        t = umax;  // all equal
    } else {
        int hb = 31 - __builtin_clz(xorv);
        unsigned int lowmask = (hb == 31) ? 0xFFFFFFFFu : ((1u << (hb + 1)) - 1u);
        t = umax & ~lowmask;  // common prefix
        for (int bit = hb; bit >= 0; --bit) {
            unsigned int cand = t | (1u << bit);
            int c = 0;
            #pragma unroll
            for (int j = 0; j < 16; ++j) c += (u[j] >= cand) ? 1 : 0;
            #pragma unroll
            for (int off = 32; off; off >>= 1) c += __shfl_down(c, off, 64);
            __syncthreads();                 // protect s_cnt reuse across iters
            if (lane == 0) s_cnt[wid] = c;
            __syncthreads();
            c = s_cnt[0] + s_cnt[1] + s_cnt[2] + s_cnt[3];
            if (c >= kk) t = cand;
        }
    }

    // invert the order-preserving transform
    float thr = __uint_as_float((t & 0x80000000u) ? (t ^ 0x80000000u) : ~t);

    // emit selected kernel vector
    #pragma unroll
    for (int j = 0; j < 16; ++j) {
        int i = tid + j * 256;
        if (i < D) {
            float v = kern[i];
            sel[i] = (v < thr) ? 0.0f : v;
        }
    }
}

// ---------------------------------------------------------------------------
// Kernel B: out[b,d] = x[b,d] * sel[d], float4-vectorized grid-stride.
// x/out are streamed once (nontemporal); sel is 16 KiB -> L1/L2 resident.
// ---------------------------------------------------------------------------
__global__ void __launch_bounds__(256)
bcast_mul_kernel(const f32x4* __restrict__ x,
                 const f32x4* __restrict__ sel,
                 f32x4* __restrict__ out,
                 int n4, int d4mask) {
    int idx = blockIdx.x * blockDim.x + threadIdx.x;
    int stride = gridDim.x * blockDim.x;
    for (int i = idx; i < n4; i += stride) {
        f32x4 xv = __builtin_nontemporal_load(&x[i]);
        f32x4 sv = sel[i & d4mask];
        f32x4 o = xv * sv;
        __builtin_nontemporal_store(o, &out[i]);
    }
}

extern "C" void kernel_launch(void* const* d_in, const int* in_sizes, int n_in,
                              void* d_out, int out_size, void* d_ws, size_t ws_size,
                              hipStream_t stream) {
    const float* x    = (const float*)d_in[0];
    const float* kern = (const float*)d_in[1];
    const int*   kptr = (const int*)d_in[2];
    float* out = (float*)d_out;
    float* sel = (float*)d_ws;  // D floats = 16 KiB scratch

    const int D = in_sizes[1];

    // Phase 1: exact threshold + selected kernel vector (single block, ~3 us)
    select_threshold_kernel<<<1, 256, 0, stream>>>(kern, kptr, sel, D);

    // Phase 2: streaming broadcast multiply
    const int n4 = out_size / 4;          // out_size = B*D, divisible by 4
    const int d4mask = (D / 4) - 1;       // D is a power of two (4096)
    const int blocks = 2048;              // ~8 blocks/CU, grid-stride
    bcast_mul_kernel<<<blocks, 256, 0, stream>>>(
        (const f32x4*)x, (const f32x4*)sel, (f32x4*)out, n4, d4mask);
}